// Round 6
// baseline (4122.881 us; speedup 1.0000x reference)
//
#include <hip/hip_runtime.h>
#include <stdint.h>

#define HDIM 1024
#define ODIM 768
#define BDIM 256
#define TLEN 256
#define G3 (3*HDIM)

typedef __attribute__((ext_vector_type(4))) float f32x4;
typedef __attribute__((ext_vector_type(8))) short s16x8;
typedef __attribute__((ext_vector_type(2))) unsigned long long u64x2;

#define SENT64 0xFFFFFFFFFFFFFFFFull

static __device__ __forceinline__ unsigned short f2bf(float f) {
  uint32_t u = __builtin_bit_cast(uint32_t, f);
  return (unsigned short)((u + 0x7fffu + ((u >> 16) & 1u)) >> 16);
}

// ---------------- prep kernels ----------------

__global__ void k_f32_to_bf16(const float* __restrict__ in, unsigned short* __restrict__ out, int n4) {
  int i = blockIdx.x * 256 + threadIdx.x;
  if (i >= n4) return;
  float4 v = ((const float4*)in)[i];
  ushort4 o;
  o.x = f2bf(v.x); o.y = f2bf(v.y); o.z = f2bf(v.z); o.w = f2bf(v.w);
  ((ushort4*)out)[i] = o;
}

// in [R][C] f32 -> out [C][R] bf16
__global__ void k_transpose_f32_bf16(const float* __restrict__ in, unsigned short* __restrict__ out, int R, int C) {
  __shared__ float tile[32][33];
  int c0 = blockIdx.x * 32, r0 = blockIdx.y * 32;
  int tx = threadIdx.x, ty = threadIdx.y;
  #pragma unroll
  for (int i = 0; i < 32; i += 8)
    tile[ty + i][tx] = in[(size_t)(r0 + ty + i) * C + (c0 + tx)];
  __syncthreads();
  #pragma unroll
  for (int i = 0; i < 32; i += 8)
    out[(size_t)(c0 + ty + i) * R + (r0 + tx)] = f2bf(tile[tx][ty + i]);
}

// b_comb[c] = b_ih[c] + sum_o w_ih[c][o] * b_fc[o]   (fp32)
__global__ void k_bcomb(const float* __restrict__ w_ih, const float* __restrict__ b_ih,
                        const float* __restrict__ b_fc, float* __restrict__ bc) {
  int gw = (blockIdx.x * 256 + threadIdx.x) >> 6;
  int lane = threadIdx.x & 63;
  if (gw >= G3) return;
  const float* row = w_ih + (size_t)gw * ODIM;
  float s = 0.f;
  for (int o = lane; o < ODIM; o += 64) s += row[o] * b_fc[o];
  #pragma unroll
  for (int off = 32; off; off >>= 1) s += __shfl_down(s, off);
  if (lane == 0) bc[gw] = s + b_ih[gw];
}

// ---------------- generic bf16 GEMM: C[M][N] = A[M][K] * Bm[N][K]^T (+bias) ----------------
template<bool OUT_BF16, bool ADD_BIAS>
__global__ __launch_bounds__(256) void k_gemm_bt(
    const unsigned short* __restrict__ A,
    const unsigned short* __restrict__ Bm,
    const float* __restrict__ bias,
    void* __restrict__ Cout,
    int M, int N, int K)
{
  __shared__ f32x4 red[4][32][64];   // 128 KB
  int m0 = blockIdx.x * 64, n0 = blockIdx.y * 128;
  int w = threadIdx.x >> 6, lane = threadIdx.x & 63;
  int c = lane & 15, klane = (lane >> 4) << 3;
  int kpw = K >> 2, kw0 = w * kpw;
  f32x4 acc[4][8];
  #pragma unroll
  for (int mf = 0; mf < 4; mf++)
    #pragma unroll
    for (int nf = 0; nf < 8; nf++) acc[mf][nf] = f32x4{0.f, 0.f, 0.f, 0.f};

  for (int kk = 0; kk < kpw; kk += 32) {
    int kb = kw0 + kk + klane;
    s16x8 a[4], b[8];
    #pragma unroll
    for (int mf = 0; mf < 4; mf++)
      a[mf] = *(const s16x8*)(A + (size_t)(m0 + mf*16 + c) * K + kb);
    #pragma unroll
    for (int nf = 0; nf < 8; nf++)
      b[nf] = *(const s16x8*)(Bm + (size_t)(n0 + nf*16 + c) * K + kb);
    #pragma unroll
    for (int mf = 0; mf < 4; mf++)
      #pragma unroll
      for (int nf = 0; nf < 8; nf++)
        acc[mf][nf] = __builtin_amdgcn_mfma_f32_16x16x32_bf16(a[mf], b[nf], acc[mf][nf], 0, 0, 0);
  }
  #pragma unroll
  for (int mf = 0; mf < 4; mf++)
    #pragma unroll
    for (int nf = 0; nf < 8; nf++)
      red[w][mf*8+nf][lane] = acc[mf][nf];
  __syncthreads();
  #pragma unroll
  for (int nf = 0; nf < 8; nf++) {
    f32x4 s = red[0][w*8+nf][lane];
    #pragma unroll
    for (int w2 = 1; w2 < 4; w2++) s += red[w2][w*8+nf][lane];
    int col = n0 + nf*16 + c;
    float bv = 0.f;
    if constexpr (ADD_BIAS) bv = bias[col];
    int rb = m0 + w*16 + ((lane >> 4) << 2);
    #pragma unroll
    for (int i = 0; i < 4; i++) {
      float val = s[i] + bv;
      if constexpr (OUT_BF16)
        ((unsigned short*)Cout)[(size_t)(rb + i) * N + col] = f2bf(val);
      else
        ((float*)Cout)[(size_t)(rb + i) * N + col] = val;
    }
  }
}

// ---------------- persistent GRU kernel (v7 = R4 + fused output GEMM) ----------------
// R4 structure is the proven best (7.5us/step): 256 thr, 4 waves K-split,
// block-contiguous exchange, optimistic canary + sentinel backstop + repair.
// R5 refuted 2-waves/SIMD: occupancy doubled, perf dropped -> critical path
// is the inter-step exchange chain, not intra-wave latency. ~60% of each
// step both pipes idle (wait on canary/MALL RT/skew).
// v7 fills those idle slots with the OUTPUT GEMM: the step-t bulk load of
// h[t-1] (64 rows x all 1024 units, in registers) is exactly the A-operand
// for y[t-1] = h[t-1] @ w_fc^T. WGs p<48 each own 16 output cols
// [16p,16p+16): +32 MFMA/wave/step on the same a-frags vs jit-loaded w_fc
// frags (L2-hot, 32KB/WG reread per step -> transient regs, no pressure),
// cross-wave reduce piggybacks on the existing B2/B3 barriers via redY
// (16KB), y store is 64B/row coalesced f32. Post-loop: one consume-only
// pass for y[T-1]. k_gemm_hseq (~190us, re-read of all hseq) is DELETED.
// Numerics identical to k_gemm_hseq (bf16 h x bf16 wfc, f32 accum).
__global__ __launch_bounds__(256, 1) void k_gru_persist(
    const unsigned short* __restrict__ h0b,    // [B][H] bf16 initial h
    const unsigned short* __restrict__ wcomb,  // [3H][H] bf16
    const unsigned short* __restrict__ whh,    // [3H][H] bf16
    const float* __restrict__ bcomb,           // [3H]
    const float* __restrict__ bhh,             // [3H]
    const float* __restrict__ gi0,             // [B][3H] f32 (w_ih@src0+b_ih)
    const float* __restrict__ hidden0,         // [B][H] f32
    const unsigned short* __restrict__ wfc,    // [O][H] bf16
    const float* __restrict__ bfc,             // [O]
    float* __restrict__ yout,                  // [T][B][O] f32 (= d_out)
    unsigned long long* __restrict__ hx64)     // [T*64*4*256] u64 block-layout hseq (sentinel-filled)
{
  __shared__ f32x4 red[4][24][64];             // 96 KB (GRU partials)
  __shared__ f32x4 redY[4][4][64];             // 16 KB (y partials)
  __shared__ unsigned long long tile64[64][4]; // 2 KB repack tile
  unsigned short* tile = (unsigned short*)tile64;

  const int wg = blockIdx.x;
  const int mg = wg & 3, p = wg >> 2;
  const int tid = threadIdx.x;
  const int w = tid >> 6, lane = tid & 63;
  const int c = lane & 15, klane = (lane >> 4) << 3, rq = (lane >> 4) << 2;
  const int u0 = p * 16, u = u0 + c, m0 = mg * 64;
  const int wk0 = w * 256;
  const int rp = lane >> 5;                    // p' sub-offset within a ks pair (0/1)
  const int q0 = ((lane >> 4) & 1) << 1;       // u64 q within block (0/2)
  const int cprod = 16 * w + (lane & 15);      // canary producer for this lane
  const int rbl = w*16 + rq;                   // row within the 64-row block

  const bool doy = (p < 48);                   // WG-uniform: owns 16 output cols
  const float ybias = doy ? bfc[p*16 + c] : 0.f;
  const unsigned short* wfrow = wfc + (size_t)(p*16 + c) * HDIM + wk0 + klane;

  // per-lane biases (unit u), constant across t
  const float bcr = bcomb[u], bcz = bcomb[HDIM + u], bcn = bcomb[2*HDIM + u];
  const float bhr = bhh[u],   bhz = bhh[HDIM + u],   bhn = bhh[2*HDIM + u];

  // load weight b-frags into registers: wr[gate][kstep]  (192 regs, AV file)
  s16x8 wr[6][8];
  #pragma unroll
  for (int g = 0; g < 6; g++) {
    const unsigned short* W = (g < 3) ? (wcomb + (size_t)g * HDIM * HDIM)
                                      : (whh   + (size_t)(g - 3) * HDIM * HDIM);
    const unsigned short* Wrow = W + (size_t)(u0 + c) * HDIM + wk0 + klane;
    #pragma unroll
    for (int ks = 0; ks < 8; ks++)
      wr[g][ks] = *(const s16x8*)(Wrow + ks * 32);
  }

  float hcar[4];   // fp32 h carry, (r,u) fixed per thread

  #pragma unroll 1
  for (int t = 0; t < TLEN; t++) {
    // ---- A-frag acquisition ----
    s16x8 a[8][4];
    if (t == 0) {
      #pragma unroll
      for (int ks = 0; ks < 8; ks++)
        #pragma unroll
        for (int mf = 0; mf < 4; mf++)
          a[ks][mf] = *(const s16x8*)(h0b + (size_t)(m0 + mf*16 + c) * HDIM + wk0 + ks*32 + klane);
    } else {
      unsigned long long* hxp = hx64 + (size_t)(t - 1) * (64*4*256);
      // per-wave canary: lane l atomic-polls the LAST u64 of producer block
      // (cprod, mg). Heuristic gate; backstop below is the correctness.
      {
        const unsigned long long* cn = hxp + (((size_t)(cprod*4 + mg)) << 8) + 255;
        for (;;) {
          unsigned long long v = __hip_atomic_load(cn, __ATOMIC_RELAXED, __HIP_MEMORY_SCOPE_AGENT);
          if (__all(v != SENT64)) break;
          __builtin_amdgcn_s_sleep(1);
        }
      }
      // bulk fast path: coalesced 16B regular loads (half-wave reads a
      // contiguous 512B span of producer block (16w+2ks+rp, mg))
      u64x2 va[8][4];
      #pragma unroll
      for (int ks = 0; ks < 8; ks++)
        #pragma unroll
        for (int mf = 0; mf < 4; mf++)
          va[ks][mf] = *(const u64x2*)(hxp + (((size_t)((16*w + 2*ks + rp)*4 + mg)) << 8)
                                            + (size_t)(mf*16 + c)*4 + q0);
      // backstop: per-u64 sentinel validation; atomic re-poll + repair
      unsigned int bad = 0;
      #pragma unroll
      for (int ks = 0; ks < 8; ks++)
        #pragma unroll
        for (int mf = 0; mf < 4; mf++)
          bad |= (unsigned int)(va[ks][mf][0] == SENT64) | (unsigned int)(va[ks][mf][1] == SENT64);
      if (__any((int)bad)) {
        #pragma unroll
        for (int ks = 0; ks < 8; ks++)
          #pragma unroll
          for (int mf = 0; mf < 4; mf++) {
            unsigned long long* pb = hxp + (((size_t)((16*w + 2*ks + rp)*4 + mg)) << 8)
                                         + (size_t)(mf*16 + c)*4 + q0;
            #pragma unroll
            for (int hh = 0; hh < 2; hh++) {
              if (va[ks][mf][hh] == SENT64) {
                unsigned long long v;
                do {
                  v = __hip_atomic_load(pb + hh, __ATOMIC_RELAXED, __HIP_MEMORY_SCOPE_AGENT);
                } while (v == SENT64);
                pb[hh] = v;            // repair stale local-L2 line (same value, benign)
                va[ks][mf][hh] = v;
              }
            }
          }
      }
      #pragma unroll
      for (int ks = 0; ks < 8; ks++)
        #pragma unroll
        for (int mf = 0; mf < 4; mf++)
          a[ks][mf] = __builtin_bit_cast(s16x8, va[ks][mf]);
    }

    // ---- GRU MFMA phase ----
    f32x4 acc[4][6];
    #pragma unroll
    for (int mf = 0; mf < 4; mf++)
      #pragma unroll
      for (int g = 0; g < 6; g++) acc[mf][g] = f32x4{0.f, 0.f, 0.f, 0.f};
    #pragma unroll
    for (int ks = 0; ks < 8; ks++)
      #pragma unroll
      for (int g = 0; g < 6; g++)
        #pragma unroll
        for (int mf = 0; mf < 4; mf++)
          acc[mf][g] = __builtin_amdgcn_mfma_f32_16x16x32_bf16(a[ks][mf], wr[g][ks], acc[mf][g], 0, 0, 0);

    // ---- fused output-GEMM MFMA: y[t-1] partial over this wave's K-quarter ----
    // same a-frags; w_fc frags jit-loaded (L2-hot), transient registers.
    f32x4 yacc[4];
    if (doy && t > 0) {
      #pragma unroll
      for (int mf = 0; mf < 4; mf++) yacc[mf] = f32x4{0.f, 0.f, 0.f, 0.f};
      #pragma unroll
      for (int ks = 0; ks < 8; ks++) {
        s16x8 wf = *(const s16x8*)(wfrow + ks * 32);
        #pragma unroll
        for (int mf = 0; mf < 4; mf++)
          yacc[mf] = __builtin_amdgcn_mfma_f32_16x16x32_bf16(a[ks][mf], wf, yacc[mf], 0, 0, 0);
      }
    }

    // ---- cross-wave K-reduce: wave w keeps m-frag mf==w ----
    #pragma unroll
    for (int mf = 0; mf < 4; mf++) {
      if (mf != w) {
        #pragma unroll
        for (int g = 0; g < 6; g++) red[w][mf*6 + g][lane] = acc[mf][g];
      }
    }
    if (doy && t > 0) {
      #pragma unroll
      for (int mf = 0; mf < 4; mf++)
        if (mf != w) redY[w][mf][lane] = yacc[mf];
    }
    f32x4 s[6];
    #pragma unroll
    for (int mf = 0; mf < 4; mf++) {
      if (mf == w) {
        #pragma unroll
        for (int g = 0; g < 6; g++) s[g] = acc[mf][g];
      }
    }
    __syncthreads();   // B2: red writes complete
    #pragma unroll
    for (int w2 = 0; w2 < 4; w2++) {
      if (w2 != w) {
        #pragma unroll
        for (int g = 0; g < 6; g++) s[g] += red[w2][w*6 + g][lane];
      }
    }
    f32x4 ysum;
    if (doy && t > 0) {
      ysum = yacc[w];
      #pragma unroll
      for (int w2 = 0; w2 < 4; w2++)
        if (w2 != w) ysum += redY[w2][w][lane];
    }
    __syncthreads();   // B3: red consumed -> next step's writes are safe.
                       // (Before publish, so no barrier waits on publish vmcnt.)

    // ---- epilogue: rows m0 + rbl + i, unit u ----
    #pragma unroll
    for (int i = 0; i < 4; i++) {
      int r = m0 + rbl + i;
      float gir, giz, gin;
      if (t == 0) {
        gir = gi0[(size_t)r * G3 + u];
        giz = gi0[(size_t)r * G3 + HDIM + u];
        gin = gi0[(size_t)r * G3 + 2*HDIM + u];
        hcar[i] = hidden0[(size_t)r * HDIM + u];
      } else {
        gir = s[0][i] + bcr; giz = s[1][i] + bcz; gin = s[2][i] + bcn;
      }
      float ghr = s[3][i] + bhr, ghz = s[4][i] + bhz, ghn = s[5][i] + bhn;
      float rg = 1.f / (1.f + __expf(-(gir + ghr)));
      float zg = 1.f / (1.f + __expf(-(giz + ghz)));
      float pn = gin + rg * ghn;
      pn = fminf(fmaxf(pn, -15.f), 15.f);
      float e2 = __expf(2.f * pn);
      float ng = (e2 - 1.f) / (e2 + 1.f);
      float hv = (1.f - zg) * ng + zg * hcar[i];
      hcar[i] = hv;                              // register carry
      tile[(rbl + i) * 16 + c] = f2bf(hv);       // LDS repack (intra-wave rows)
    }

    // ---- publish: one contiguous 2KB block per (WG,t) (full 64B lines) ----
    {
      unsigned long long v = tile64[tid >> 2][tid & 3];
      unsigned long long* dst = hx64 + (size_t)t * (64*4*256)
                              + (((size_t)(p*4 + mg)) << 8) + tid;
      __hip_atomic_store(dst, v, __ATOMIC_RELAXED, __HIP_MEMORY_SCOPE_AGENT);
    }

    // ---- y[t-1] store (after publish so consumers aren't delayed) ----
    if (doy && t > 0) {
      #pragma unroll
      for (int i = 0; i < 4; i++) {
        int r = m0 + rbl + i;
        yout[((size_t)(t - 1) * BDIM + r) * ODIM + p*16 + c] = ysum[i] + ybias;
      }
    }
  }

  // ---- post-loop: y[T-1] from step T-1 publishes (consume-only pass) ----
  if (doy) {
    unsigned long long* hxp = hx64 + (size_t)(TLEN - 1) * (64*4*256);
    {
      const unsigned long long* cn = hxp + (((size_t)(cprod*4 + mg)) << 8) + 255;
      for (;;) {
        unsigned long long v = __hip_atomic_load(cn, __ATOMIC_RELAXED, __HIP_MEMORY_SCOPE_AGENT);
        if (__all(v != SENT64)) break;
        __builtin_amdgcn_s_sleep(1);
      }
    }
    u64x2 va[8][4];
    #pragma unroll
    for (int ks = 0; ks < 8; ks++)
      #pragma unroll
      for (int mf = 0; mf < 4; mf++)
        va[ks][mf] = *(const u64x2*)(hxp + (((size_t)((16*w + 2*ks + rp)*4 + mg)) << 8)
                                          + (size_t)(mf*16 + c)*4 + q0);
    unsigned int bad = 0;
    #pragma unroll
    for (int ks = 0; ks < 8; ks++)
      #pragma unroll
      for (int mf = 0; mf < 4; mf++)
        bad |= (unsigned int)(va[ks][mf][0] == SENT64) | (unsigned int)(va[ks][mf][1] == SENT64);
    if (__any((int)bad)) {
      #pragma unroll
      for (int ks = 0; ks < 8; ks++)
        #pragma unroll
        for (int mf = 0; mf < 4; mf++) {
          unsigned long long* pb = hxp + (((size_t)((16*w + 2*ks + rp)*4 + mg)) << 8)
                                       + (size_t)(mf*16 + c)*4 + q0;
          #pragma unroll
          for (int hh = 0; hh < 2; hh++) {
            if (va[ks][mf][hh] == SENT64) {
              unsigned long long v;
              do {
                v = __hip_atomic_load(pb + hh, __ATOMIC_RELAXED, __HIP_MEMORY_SCOPE_AGENT);
              } while (v == SENT64);
              pb[hh] = v;
              va[ks][mf][hh] = v;
            }
          }
        }
    }
    f32x4 yacc[4];
    #pragma unroll
    for (int mf = 0; mf < 4; mf++) yacc[mf] = f32x4{0.f, 0.f, 0.f, 0.f};
    #pragma unroll
    for (int ks = 0; ks < 8; ks++) {
      s16x8 wf = *(const s16x8*)(wfrow + ks * 32);
      #pragma unroll
      for (int mf = 0; mf < 4; mf++)
        yacc[mf] = __builtin_amdgcn_mfma_f32_16x16x32_bf16(
            __builtin_bit_cast(s16x8, va[ks][mf]), wf, yacc[mf], 0, 0, 0);
    }
    #pragma unroll
    for (int mf = 0; mf < 4; mf++)
      if (mf != w) redY[w][mf][lane] = yacc[mf];
    __syncthreads();
    f32x4 ysum = yacc[w];
    #pragma unroll
    for (int w2 = 0; w2 < 4; w2++)
      if (w2 != w) ysum += redY[w2][w][lane];
    #pragma unroll
    for (int i = 0; i < 4; i++) {
      int r = m0 + rbl + i;
      yout[((size_t)(TLEN - 1) * BDIM + r) * ODIM + p*16 + c] = ysum[i] + ybias;
    }
  }
}

// ---------------- fallback per-step GRU (only if workspace too small) ----------------
__global__ __launch_bounds__(256) void k_gru_step(
    const unsigned short* __restrict__ A1, int K1,
    const unsigned short* __restrict__ W1,
    const float* __restrict__ b1,
    const unsigned short* __restrict__ A2,
    const unsigned short* __restrict__ W2,
    const float* __restrict__ b2,
    const float* __restrict__ hprev,
    float* __restrict__ hout,
    unsigned short* __restrict__ hseq,
    int fused)
{
  __shared__ f32x4 red[4][24][64];
  int ublk = blockIdx.x & 63, mg = blockIdx.x >> 6;
  int u0 = ublk * 16, m0 = mg * 64;
  int w = threadIdx.x >> 6, lane = threadIdx.x & 63;
  int c = lane & 15, klane = (lane >> 4) << 3;
  f32x4 acc[6][4];
  #pragma unroll
  for (int g = 0; g < 6; g++)
    #pragma unroll
    for (int mf = 0; mf < 4; mf++) acc[g][mf] = f32x4{0.f, 0.f, 0.f, 0.f};

  if (fused) {
    const int kpw = HDIM >> 2;
    int kw0 = w * kpw;
    for (int kk = 0; kk < kpw; kk += 32) {
      int kb = kw0 + kk + klane;
      s16x8 a[4], bg[6];
      #pragma unroll
      for (int mf = 0; mf < 4; mf++)
        a[mf] = *(const s16x8*)(A2 + (size_t)(m0 + mf*16 + c) * HDIM + kb);
      #pragma unroll
      for (int g = 0; g < 3; g++) {
        bg[g]   = *(const s16x8*)(W1 + (size_t)(g*HDIM + u0 + c) * HDIM + kb);
        bg[g+3] = *(const s16x8*)(W2 + (size_t)(g*HDIM + u0 + c) * HDIM + kb);
      }
      #pragma unroll
      for (int g = 0; g < 6; g++)
        #pragma unroll
        for (int mf = 0; mf < 4; mf++)
          acc[g][mf] = __builtin_amdgcn_mfma_f32_16x16x32_bf16(a[mf], bg[g], acc[g][mf], 0, 0, 0);
    }
  } else {
    {
      int kpw = K1 >> 2, kw0 = w * kpw;
      for (int kk = 0; kk < kpw; kk += 32) {
        int kb = kw0 + kk + klane;
        s16x8 a[4], bg[3];
        #pragma unroll
        for (int mf = 0; mf < 4; mf++)
          a[mf] = *(const s16x8*)(A1 + (size_t)(m0 + mf*16 + c) * K1 + kb);
        #pragma unroll
        for (int g = 0; g < 3; g++)
          bg[g] = *(const s16x8*)(W1 + (size_t)(g*HDIM + u0 + c) * K1 + kb);
        #pragma unroll
        for (int g = 0; g < 3; g++)
          #pragma unroll
          for (int mf = 0; mf < 4; mf++)
            acc[g][mf] = __builtin_amdgcn_mfma_f32_16x16x32_bf16(a[mf], bg[g], acc[g][mf], 0, 0, 0);
      }
    }
    {
      int kpw = HDIM >> 2, kw0 = w * kpw;
      for (int kk = 0; kk < kpw; kk += 32) {
        int kb = kw0 + kk + klane;
        s16x8 a[4], bg[3];
        #pragma unroll
        for (int mf = 0; mf < 4; mf++)
          a[mf] = *(const s16x8*)(A2 + (size_t)(m0 + mf*16 + c) * HDIM + kb);
        #pragma unroll
        for (int g = 0; g < 3; g++)
          bg[g] = *(const s16x8*)(W2 + (size_t)(g*HDIM + u0 + c) * HDIM + kb);
        #pragma unroll
        for (int g = 0; g < 3; g++)
          #pragma unroll
          for (int mf = 0; mf < 4; mf++)
            acc[g+3][mf] = __builtin_amdgcn_mfma_f32_16x16x32_bf16(a[mf], bg[g], acc[g+3][mf], 0, 0, 0);
      }
    }
  }

  #pragma unroll
  for (int g = 0; g < 6; g++)
    #pragma unroll
    for (int mf = 0; mf < 4; mf++)
      red[w][g*4+mf][lane] = acc[g][mf];
  __syncthreads();

  f32x4 gg[6];
  #pragma unroll
  for (int g = 0; g < 6; g++) {
    f32x4 sum = red[0][g*4+w][lane];
    #pragma unroll
    for (int w2 = 1; w2 < 4; w2++) sum += red[w2][g*4+w][lane];
    gg[g] = sum;
  }
  int u = u0 + c;
  float b1r = b1[u], b1z = b1[HDIM+u], b1n = b1[2*HDIM+u];
  float b2r = b2[u], b2z = b2[HDIM+u], b2n = b2[2*HDIM+u];
  int rb = m0 + w*16 + ((lane >> 4) << 2);
  #pragma unroll
  for (int i = 0; i < 4; i++) {
    float pre_r = gg[0][i] + b1r + gg[3][i] + b2r;
    float pre_z = gg[1][i] + b1z + gg[4][i] + b2z;
    float ghn  = gg[5][i] + b2n;
    float r = 1.f / (1.f + __expf(-pre_r));
    float z = 1.f / (1.f + __expf(-pre_z));
    float pn = gg[2][i] + b1n + r * ghn;
    pn = fminf(fmaxf(pn, -15.f), 15.f);
    float e2 = __expf(2.f * pn);
    float n = (e2 - 1.f) / (e2 + 1.f);
    size_t idx = (size_t)(rb + i) * HDIM + u;
    float hp = hprev[idx];
    float hn = (1.f - z) * n + z * hp;
    hout[idx] = hn;
    hseq[idx] = f2bf(hn);
  }
}

// ---------------- host ----------------

extern "C" void kernel_launch(void* const* d_in, const int* in_sizes, int n_in,
                              void* d_out, int out_size, void* d_ws, size_t ws_size,
                              hipStream_t stream) {
  const float* src    = (const float*)d_in[0];
  const float* hidden = (const float*)d_in[2];
  const float* w_ih   = (const float*)d_in[3];
  const float* w_hh   = (const float*)d_in[4];
  const float* b_ih   = (const float*)d_in[5];
  const float* b_hh   = (const float*)d_in[6];
  const float* w_fc   = (const float*)d_in[7];
  const float* b_fc   = (const float*)d_in[8];
  float* out = (float*)d_out;

  uint8_t* ws = (uint8_t*)d_ws;
  size_t off = 0;
  auto alloc = [&](size_t bytes) -> void* {
    void* pp = ws + off;
    off += (bytes + 255) & ~(size_t)255;
    return pp;
  };
  unsigned short* wih_b  = (unsigned short*)alloc((size_t)G3*ODIM*2);
  unsigned short* whh_b  = (unsigned short*)alloc((size_t)G3*HDIM*2);
  unsigned short* wfc_b  = (unsigned short*)alloc((size_t)ODIM*HDIM*2);
  unsigned short* wfcT_b = (unsigned short*)alloc((size_t)HDIM*ODIM*2);
  unsigned short* wcomb  = (unsigned short*)alloc((size_t)G3*HDIM*2);
  unsigned short* src0_b = (unsigned short*)alloc((size_t)BDIM*ODIM*2);
  unsigned short* h0_b   = (unsigned short*)alloc((size_t)BDIM*HDIM*2);
  float* bcomb = (float*)alloc((size_t)G3*4);
  float* hbuf0 = (float*)alloc((size_t)BDIM*HDIM*4);
  float* hbuf1 = (float*)alloc((size_t)BDIM*HDIM*4);
  unsigned short* hpp = (unsigned short*)alloc((size_t)2*BDIM*HDIM*2);
  unsigned short* hseq = (unsigned short*)alloc((size_t)TLEN*BDIM*HDIM*2);
  float* gi0 = (float*)alloc((size_t)BDIM*G3*4);
  bool big = (off <= ws_size);   // persistent path needs everything

  // prep
  k_f32_to_bf16<<<G3*ODIM/4/256, 256, 0, stream>>>(w_ih, wih_b, G3*ODIM/4);
  k_f32_to_bf16<<<G3*HDIM/4/256, 256, 0, stream>>>(w_hh, whh_b, G3*HDIM/4);
  k_f32_to_bf16<<<ODIM*HDIM/4/256, 256, 0, stream>>>(w_fc, wfc_b, ODIM*HDIM/4);
  k_f32_to_bf16<<<BDIM*ODIM/4/256, 256, 0, stream>>>(src, src0_b, BDIM*ODIM/4);
  k_f32_to_bf16<<<BDIM*HDIM/4/256, 256, 0, stream>>>(hidden, h0_b, BDIM*HDIM/4);
  k_transpose_f32_bf16<<<dim3(HDIM/32, ODIM/32), dim3(32, 8), 0, stream>>>(w_fc, wfcT_b, ODIM, HDIM);
  k_gemm_bt<true, false><<<dim3(G3/64, HDIM/128), 256, 0, stream>>>(wih_b, wfcT_b, nullptr, wcomb, G3, HDIM, ODIM);
  k_bcomb<<<G3/4, 256, 0, stream>>>(w_ih, b_ih, b_fc, bcomb);

  if (big) {
    // sentinel-fill the exchange buffer (REQUIRED every call: harness does
    // not re-poison between replays; protocol self-syncs on 0xFF)
    hipMemsetAsync(hseq, 0xFF, (size_t)TLEN*BDIM*HDIM*2, stream);
    // gi0 = src0 @ w_ih^T + b_ih  (f32, exact input for step 0)
    k_gemm_bt<false, true><<<dim3(BDIM/64, G3/128), 256, 0, stream>>>(
        src0_b, wih_b, b_ih, gi0, BDIM, G3, ODIM);
    // persistent GRU with fused output GEMM (writes all of out)
    k_gru_persist<<<256, 256, 0, stream>>>(h0_b, wcomb, whh_b, bcomb, b_hh,
                                           gi0, hidden, wfc_b, b_fc, out,
                                           (unsigned long long*)hseq);
  } else {
    for (int t = 0; t < TLEN; t++) {
      const unsigned short* aprev = (t == 0) ? h0_b : hpp + (size_t)((t-1)&1)*BDIM*HDIM;
      unsigned short* hs_cur = hpp + (size_t)(t&1)*BDIM*HDIM;
      const float* hprev_f = (t == 0) ? hidden : ((t & 1) ? hbuf0 : hbuf1);
      float* hout_f = (t & 1) ? hbuf1 : hbuf0;
      if (t == 0) {
        k_gru_step<<<256, 256, 0, stream>>>(src0_b, ODIM, wih_b, b_ih,
            aprev, whh_b, b_hh, hprev_f, hout_f, hs_cur, 0);
      } else {
        k_gru_step<<<256, 256, 0, stream>>>(aprev, HDIM, wcomb, bcomb,
            aprev, whh_b, b_hh, hprev_f, hout_f, hs_cur, 1);
      }
      k_gemm_bt<false, true><<<dim3(BDIM/64, ODIM/128), 256, 0, stream>>>(
          hs_cur, wfc_b, b_fc, out + (size_t)t*BDIM*ODIM, BDIM, ODIM, HDIM);
    }
  }
}

// Round 8
// 4109.624 us; speedup vs baseline: 1.0032x; 1.0032x over previous
//
#include <hip/hip_runtime.h>
#include <stdint.h>

#define HDIM 1024
#define ODIM 768
#define BDIM 256
#define TLEN 256
#define G3 (3*HDIM)

typedef __attribute__((ext_vector_type(4))) float f32x4;
typedef __attribute__((ext_vector_type(8))) short s16x8;
typedef __attribute__((ext_vector_type(2))) unsigned long long u64x2;

#define SENT64 0xFFFFFFFFFFFFFFFFull

static __device__ __forceinline__ unsigned short f2bf(float f) {
  uint32_t u = __builtin_bit_cast(uint32_t, f);
  return (unsigned short)((u + 0x7fffu + ((u >> 16) & 1u)) >> 16);
}
static __device__ __forceinline__ float bf2f(unsigned short u) {
  return __builtin_bit_cast(float, ((uint32_t)u) << 16);
}

// ---------------- prep kernels ----------------

__global__ void k_f32_to_bf16(const float* __restrict__ in, unsigned short* __restrict__ out, int n4) {
  int i = blockIdx.x * 256 + threadIdx.x;
  if (i >= n4) return;
  float4 v = ((const float4*)in)[i];
  ushort4 o;
  o.x = f2bf(v.x); o.y = f2bf(v.y); o.z = f2bf(v.z); o.w = f2bf(v.w);
  ((ushort4*)out)[i] = o;
}

// in [R][C] f32 -> out [C][R] bf16
__global__ void k_transpose_f32_bf16(const float* __restrict__ in, unsigned short* __restrict__ out, int R, int C) {
  __shared__ float tile[32][33];
  int c0 = blockIdx.x * 32, r0 = blockIdx.y * 32;
  int tx = threadIdx.x, ty = threadIdx.y;
  #pragma unroll
  for (int i = 0; i < 32; i += 8)
    tile[ty + i][tx] = in[(size_t)(r0 + ty + i) * C + (c0 + tx)];
  __syncthreads();
  #pragma unroll
  for (int i = 0; i < 32; i += 8)
    out[(size_t)(c0 + ty + i) * R + (r0 + tx)] = f2bf(tile[tx][ty + i]);
}

// b_comb[c] = b_ih[c] + sum_o w_ih[c][o] * b_fc[o]   (fp32)
__global__ void k_bcomb(const float* __restrict__ w_ih, const float* __restrict__ b_ih,
                        const float* __restrict__ b_fc, float* __restrict__ bc) {
  int gw = (blockIdx.x * 256 + threadIdx.x) >> 6;
  int lane = threadIdx.x & 63;
  if (gw >= G3) return;
  const float* row = w_ih + (size_t)gw * ODIM;
  float s = 0.f;
  for (int o = lane; o < ODIM; o += 64) s += row[o] * b_fc[o];
  #pragma unroll
  for (int off = 32; off; off >>= 1) s += __shfl_down(s, off);
  if (lane == 0) bc[gw] = s + b_ih[gw];
}

// unblock y: ybf blocked u16 idx = (((t*48+p)*4+mg)*64 + row)*16 + col
// -> out[t][mg*64+row][p*16+col] f32. One WG per (t,p); thread = mg*64+row.
__global__ __launch_bounds__(256) void k_y_unblock(
    const unsigned short* __restrict__ yb, float* __restrict__ out) {
  int t = blockIdx.x / 48, p = blockIdx.x % 48;
  int mg = threadIdx.x >> 6, row = threadIdx.x & 63;
  const unsigned short* src = yb + ((((size_t)t*48 + p)*4 + mg)*64 + row)*16;
  s16x8 v0 = *(const s16x8*)(src);
  s16x8 v1 = *(const s16x8*)(src + 8);
  float* dst = out + ((size_t)t*BDIM + mg*64 + row)*ODIM + p*16;
  float4 f0, f1, f2, f3;
  f0.x = bf2f((unsigned short)v0[0]); f0.y = bf2f((unsigned short)v0[1]);
  f0.z = bf2f((unsigned short)v0[2]); f0.w = bf2f((unsigned short)v0[3]);
  f1.x = bf2f((unsigned short)v0[4]); f1.y = bf2f((unsigned short)v0[5]);
  f1.z = bf2f((unsigned short)v0[6]); f1.w = bf2f((unsigned short)v0[7]);
  f2.x = bf2f((unsigned short)v1[0]); f2.y = bf2f((unsigned short)v1[1]);
  f2.z = bf2f((unsigned short)v1[2]); f2.w = bf2f((unsigned short)v1[3]);
  f3.x = bf2f((unsigned short)v1[4]); f3.y = bf2f((unsigned short)v1[5]);
  f3.z = bf2f((unsigned short)v1[6]); f3.w = bf2f((unsigned short)v1[7]);
  ((float4*)dst)[0] = f0; ((float4*)dst)[1] = f1;
  ((float4*)dst)[2] = f2; ((float4*)dst)[3] = f3;
}

// ---------------- generic bf16 GEMM: C[M][N] = A[M][K] * Bm[N][K]^T (+bias) ----------------
template<bool OUT_BF16, bool ADD_BIAS>
__global__ __launch_bounds__(256) void k_gemm_bt(
    const unsigned short* __restrict__ A,
    const unsigned short* __restrict__ Bm,
    const float* __restrict__ bias,
    void* __restrict__ Cout,
    int M, int N, int K)
{
  __shared__ f32x4 red[4][32][64];   // 128 KB
  int m0 = blockIdx.x * 64, n0 = blockIdx.y * 128;
  int w = threadIdx.x >> 6, lane = threadIdx.x & 63;
  int c = lane & 15, klane = (lane >> 4) << 3;
  int kpw = K >> 2, kw0 = w * kpw;
  f32x4 acc[4][8];
  #pragma unroll
  for (int mf = 0; mf < 4; mf++)
    #pragma unroll
    for (int nf = 0; nf < 8; nf++) acc[mf][nf] = f32x4{0.f, 0.f, 0.f, 0.f};

  for (int kk = 0; kk < kpw; kk += 32) {
    int kb = kw0 + kk + klane;
    s16x8 a[4], b[8];
    #pragma unroll
    for (int mf = 0; mf < 4; mf++)
      a[mf] = *(const s16x8*)(A + (size_t)(m0 + mf*16 + c) * K + kb);
    #pragma unroll
    for (int nf = 0; nf < 8; nf++)
      b[nf] = *(const s16x8*)(Bm + (size_t)(n0 + nf*16 + c) * K + kb);
    #pragma unroll
    for (int mf = 0; mf < 4; mf++)
      #pragma unroll
      for (int nf = 0; nf < 8; nf++)
        acc[mf][nf] = __builtin_amdgcn_mfma_f32_16x16x32_bf16(a[mf], b[nf], acc[mf][nf], 0, 0, 0);
  }
  #pragma unroll
  for (int mf = 0; mf < 4; mf++)
    #pragma unroll
    for (int nf = 0; nf < 8; nf++)
      red[w][mf*8+nf][lane] = acc[mf][nf];
  __syncthreads();
  #pragma unroll
  for (int nf = 0; nf < 8; nf++) {
    f32x4 s = red[0][w*8+nf][lane];
    #pragma unroll
    for (int w2 = 1; w2 < 4; w2++) s += red[w2][w*8+nf][lane];
    int col = n0 + nf*16 + c;
    float bv = 0.f;
    if constexpr (ADD_BIAS) bv = bias[col];
    int rb = m0 + w*16 + ((lane >> 4) << 2);
    #pragma unroll
    for (int i = 0; i < 4; i++) {
      float val = s[i] + bv;
      if constexpr (OUT_BF16)
        ((unsigned short*)Cout)[(size_t)(rb + i) * N + col] = f2bf(val);
      else
        ((float*)Cout)[(size_t)(rb + i) * N + col] = val;
    }
  }
}

// ---------------- output GEMM over block-layout hseq (non-fused fallback) ----------------
// A is hseq in BLOCK layout: u64 index = ((t*64 + p')*4 + mg)*256 + rowl*4 + q
__global__ __launch_bounds__(256) void k_gemm_hseq(
    const unsigned long long* __restrict__ Ahx,
    const unsigned short* __restrict__ Bm,
    const float* __restrict__ bias,
    float* __restrict__ Cout)
{
  const int N = ODIM, K = HDIM;
  __shared__ f32x4 red[4][32][64];   // 128 KB
  int m0 = blockIdx.x * 64, n0 = blockIdx.y * 128;
  int w = threadIdx.x >> 6, lane = threadIdx.x & 63;
  int c = lane & 15, klane = (lane >> 4) << 3;
  int kpw = K >> 2, kw0 = w * kpw;
  const int tb = m0 >> 8, mgb = (m0 >> 6) & 3;
  f32x4 acc[4][8];
  #pragma unroll
  for (int mf = 0; mf < 4; mf++)
    #pragma unroll
    for (int nf = 0; nf < 8; nf++) acc[mf][nf] = f32x4{0.f, 0.f, 0.f, 0.f};

  for (int kk = 0; kk < kpw; kk += 32) {
    int kb = kw0 + kk + klane;
    int uk = kb >> 2;
    s16x8 a[4], b[8];
    #pragma unroll
    for (int mf = 0; mf < 4; mf++)
      a[mf] = *(const s16x8*)(Ahx + (((size_t)((tb*64 + (uk>>2))*4 + mgb)) << 8)
                                   + (size_t)(mf*16 + c)*4 + (uk & 3));
    #pragma unroll
    for (int nf = 0; nf < 8; nf++)
      b[nf] = *(const s16x8*)(Bm + (size_t)(n0 + nf*16 + c) * K + kb);
    #pragma unroll
    for (int mf = 0; mf < 4; mf++)
      #pragma unroll
      for (int nf = 0; nf < 8; nf++)
        acc[mf][nf] = __builtin_amdgcn_mfma_f32_16x16x32_bf16(a[mf], b[nf], acc[mf][nf], 0, 0, 0);
  }
  #pragma unroll
  for (int mf = 0; mf < 4; mf++)
    #pragma unroll
    for (int nf = 0; nf < 8; nf++)
      red[w][mf*8+nf][lane] = acc[mf][nf];
  __syncthreads();
  #pragma unroll
  for (int nf = 0; nf < 8; nf++) {
    f32x4 s = red[0][w*8+nf][lane];
    #pragma unroll
    for (int w2 = 1; w2 < 4; w2++) s += red[w2][w*8+nf][lane];
    int col = n0 + nf*16 + c;
    float bv = bias[col];
    int rb = m0 + w*16 + ((lane >> 4) << 2);
    #pragma unroll
    for (int i = 0; i < 4; i++)
      Cout[(size_t)(rb + i) * N + col] = s[i] + bv;
  }
}

// ---------------- persistent GRU kernel (v9 = R6-proven ordering + safe fusion) ----------------
// R7 post-mortem: bundling {wf-regs, nt-stores, y-after-publish} onto R6 NaN'd;
// nt-store semantics vs harness's pre-launch memset dirty-zero L2 lines is the
// unverifiable suspect. v9 retreats to R6's EXACT passing ordering (y-MFMA
// pre-reduce, redY around B2, y-store after publish) and re-applies only
// fully-understood changes:
//  - wf[8] persistent regs (kills R6's 1.5GB per-step w_fc re-reads)
//  - y stored as bf16 into a 75MB BLOCKED workspace (2KB full-line blocks per
//    (WG,t)) instead of 201MB f32 to out: MALL set hseq128+ybf75+wts < 256MB
//    -> no thrash (R6's second failure cause), no nt needed. k_y_unblock
//    converts to f32 out afterwards (~60us). Precision: +<=0.5 bf16 ULP on y.
//  - ykeep explicit unroll (no runtime-indexed ext_vector, rule #20).
// doy = (p<48) && ybf!=nullptr; with ybf==nullptr this kernel is exactly R4's.
__global__ __launch_bounds__(256, 1) void k_gru_persist(
    const unsigned short* __restrict__ h0b,    // [B][H] bf16 initial h
    const unsigned short* __restrict__ wcomb,  // [3H][H] bf16
    const unsigned short* __restrict__ whh,    // [3H][H] bf16
    const float* __restrict__ bcomb,           // [3H]
    const float* __restrict__ bhh,             // [3H]
    const float* __restrict__ gi0,             // [B][3H] f32 (w_ih@src0+b_ih)
    const float* __restrict__ hidden0,         // [B][H] f32
    const unsigned short* __restrict__ wfc,    // [O][H] bf16
    const float* __restrict__ bfc,             // [O]
    unsigned short* __restrict__ ybf,          // blocked y bf16 (or nullptr)
    unsigned long long* __restrict__ hx64)     // [T*64*4*256] u64 block-layout hseq (sentinel-filled)
{
  __shared__ f32x4 red[4][24][64];             // 96 KB (GRU partials)
  __shared__ f32x4 redY[4][4][64];             // 16 KB (y partials)
  __shared__ unsigned long long tile64[64][4]; // 2 KB repack tile
  unsigned short* tile = (unsigned short*)tile64;

  const int wg = blockIdx.x;
  const int mg = wg & 3, p = wg >> 2;
  const int tid = threadIdx.x;
  const int w = tid >> 6, lane = tid & 63;
  const int c = lane & 15, klane = (lane >> 4) << 3, rq = (lane >> 4) << 2;
  const int u0 = p * 16, u = u0 + c, m0 = mg * 64;
  const int wk0 = w * 256;
  const int rp = lane >> 5;                    // p' sub-offset within a ks pair (0/1)
  const int q0 = ((lane >> 4) & 1) << 1;       // u64 q within block (0/2)
  const int cprod = 16 * w + (lane & 15);      // canary producer for this lane
  const int rbl = w*16 + rq;                   // row within the 64-row block

  const bool doy = (p < 48) && (ybf != nullptr);
  const float ybias = doy ? bfc[p*16 + c] : 0.f;

  // per-lane biases (unit u), constant across t
  const float bcr = bcomb[u], bcz = bcomb[HDIM + u], bcn = bcomb[2*HDIM + u];
  const float bhr = bhh[u],   bhz = bhh[HDIM + u],   bhn = bhh[2*HDIM + u];

  // GRU weight b-frags: wr[gate][kstep] (192 regs, AV file)
  s16x8 wr[6][8];
  #pragma unroll
  for (int g = 0; g < 6; g++) {
    const unsigned short* W = (g < 3) ? (wcomb + (size_t)g * HDIM * HDIM)
                                      : (whh   + (size_t)(g - 3) * HDIM * HDIM);
    const unsigned short* Wrow = W + (size_t)(u0 + c) * HDIM + wk0 + klane;
    #pragma unroll
    for (int ks = 0; ks < 8; ks++)
      wr[g][ks] = *(const s16x8*)(Wrow + ks * 32);
  }
  // w_fc b-frags (16 output cols of this WG, this wave's K-quarter): persistent (32 regs)
  s16x8 wf[8];
  if (doy) {
    const unsigned short* wfrow = wfc + (size_t)(p*16 + c) * HDIM + wk0 + klane;
    #pragma unroll
    for (int ks = 0; ks < 8; ks++)
      wf[ks] = *(const s16x8*)(wfrow + ks * 32);
  }

  float hcar[4];   // fp32 h carry, (r,u) fixed per thread

  #pragma unroll 1
  for (int t = 0; t < TLEN; t++) {
    // ---- A-frag acquisition ----
    s16x8 a[8][4];
    if (t == 0) {
      #pragma unroll
      for (int ks = 0; ks < 8; ks++)
        #pragma unroll
        for (int mf = 0; mf < 4; mf++)
          a[ks][mf] = *(const s16x8*)(h0b + (size_t)(m0 + mf*16 + c) * HDIM + wk0 + ks*32 + klane);
    } else {
      unsigned long long* hxp = hx64 + (size_t)(t - 1) * (64*4*256);
      // per-wave canary: lane l atomic-polls the LAST u64 of producer block
      // (cprod, mg). Heuristic gate; backstop below is the correctness.
      {
        const unsigned long long* cn = hxp + (((size_t)(cprod*4 + mg)) << 8) + 255;
        for (;;) {
          unsigned long long v = __hip_atomic_load(cn, __ATOMIC_RELAXED, __HIP_MEMORY_SCOPE_AGENT);
          if (__all(v != SENT64)) break;
          __builtin_amdgcn_s_sleep(1);
        }
      }
      // bulk fast path: coalesced 16B regular loads
      u64x2 va[8][4];
      #pragma unroll
      for (int ks = 0; ks < 8; ks++)
        #pragma unroll
        for (int mf = 0; mf < 4; mf++)
          va[ks][mf] = *(const u64x2*)(hxp + (((size_t)((16*w + 2*ks + rp)*4 + mg)) << 8)
                                            + (size_t)(mf*16 + c)*4 + q0);
      // backstop: per-u64 sentinel validation; atomic re-poll + repair
      unsigned int bad = 0;
      #pragma unroll
      for (int ks = 0; ks < 8; ks++)
        #pragma unroll
        for (int mf = 0; mf < 4; mf++)
          bad |= (unsigned int)(va[ks][mf][0] == SENT64) | (unsigned int)(va[ks][mf][1] == SENT64);
      if (__any((int)bad)) {
        #pragma unroll
        for (int ks = 0; ks < 8; ks++)
          #pragma unroll
          for (int mf = 0; mf < 4; mf++) {
            unsigned long long* pb = hxp + (((size_t)((16*w + 2*ks + rp)*4 + mg)) << 8)
                                         + (size_t)(mf*16 + c)*4 + q0;
            #pragma unroll
            for (int hh = 0; hh < 2; hh++) {
              if (va[ks][mf][hh] == SENT64) {
                unsigned long long v;
                do {
                  v = __hip_atomic_load(pb + hh, __ATOMIC_RELAXED, __HIP_MEMORY_SCOPE_AGENT);
                } while (v == SENT64);
                pb[hh] = v;            // repair stale local-L2 line (same value, benign)
                va[ks][mf][hh] = v;
              }
            }
          }
      }
      #pragma unroll
      for (int ks = 0; ks < 8; ks++)
        #pragma unroll
        for (int mf = 0; mf < 4; mf++)
          a[ks][mf] = __builtin_bit_cast(s16x8, va[ks][mf]);
    }

    // ---- GRU MFMA phase ----
    f32x4 acc[4][6];
    #pragma unroll
    for (int mf = 0; mf < 4; mf++)
      #pragma unroll
      for (int g = 0; g < 6; g++) acc[mf][g] = f32x4{0.f, 0.f, 0.f, 0.f};
    #pragma unroll
    for (int ks = 0; ks < 8; ks++)
      #pragma unroll
      for (int g = 0; g < 6; g++)
        #pragma unroll
        for (int mf = 0; mf < 4; mf++)
          acc[mf][g] = __builtin_amdgcn_mfma_f32_16x16x32_bf16(a[ks][mf], wr[g][ks], acc[mf][g], 0, 0, 0);

    // ---- y-MFMA (R6 position: pre-reduce; proven) ----
    f32x4 yacc[4];
    if (doy && t > 0) {
      #pragma unroll
      for (int mf = 0; mf < 4; mf++) yacc[mf] = f32x4{0.f, 0.f, 0.f, 0.f};
      #pragma unroll
      for (int ks = 0; ks < 8; ks++)
        #pragma unroll
        for (int mf = 0; mf < 4; mf++)
          yacc[mf] = __builtin_amdgcn_mfma_f32_16x16x32_bf16(a[ks][mf], wf[ks], yacc[mf], 0, 0, 0);
    }

    // ---- cross-wave K-reduce: wave w keeps m-frag mf==w ----
    #pragma unroll
    for (int mf = 0; mf < 4; mf++) {
      if (mf != w) {
        #pragma unroll
        for (int g = 0; g < 6; g++) red[w][mf*6 + g][lane] = acc[mf][g];
      }
    }
    f32x4 s[6];
    #pragma unroll
    for (int mf = 0; mf < 4; mf++) {
      if (mf == w) {
        #pragma unroll
        for (int g = 0; g < 6; g++) s[g] = acc[mf][g];
      }
    }
    f32x4 ykeep;
    if (doy && t > 0) {
      #pragma unroll
      for (int mf = 0; mf < 4; mf++) {
        if (mf != w) redY[w][mf][lane] = yacc[mf];
        else         ykeep = yacc[mf];
      }
    }
    __syncthreads();   // B2: red + redY writes complete
    #pragma unroll
    for (int w2 = 0; w2 < 4; w2++) {
      if (w2 != w) {
        #pragma unroll
        for (int g = 0; g < 6; g++) s[g] += red[w2][w*6 + g][lane];
      }
    }
    f32x4 ysum;
    if (doy && t > 0) {
      ysum = ykeep;
      #pragma unroll
      for (int w2 = 0; w2 < 4; w2++)
        if (w2 != w) ysum += redY[w2][w][lane];
    }
    __syncthreads();   // B3: red/redY consumed -> next step's writes safe.
                       // (Before publish, so no barrier waits on publish vmcnt.)

    // ---- epilogue: rows m0 + rbl + i, unit u ----
    #pragma unroll
    for (int i = 0; i < 4; i++) {
      int r = m0 + rbl + i;
      float gir, giz, gin;
      if (t == 0) {
        gir = gi0[(size_t)r * G3 + u];
        giz = gi0[(size_t)r * G3 + HDIM + u];
        gin = gi0[(size_t)r * G3 + 2*HDIM + u];
        hcar[i] = hidden0[(size_t)r * HDIM + u];
      } else {
        gir = s[0][i] + bcr; giz = s[1][i] + bcz; gin = s[2][i] + bcn;
      }
      float ghr = s[3][i] + bhr, ghz = s[4][i] + bhz, ghn = s[5][i] + bhn;
      float rg = 1.f / (1.f + __expf(-(gir + ghr)));
      float zg = 1.f / (1.f + __expf(-(giz + ghz)));
      float pn = gin + rg * ghn;
      pn = fminf(fmaxf(pn, -15.f), 15.f);
      float e2 = __expf(2.f * pn);
      float ng = (e2 - 1.f) / (e2 + 1.f);
      float hv = (1.f - zg) * ng + zg * hcar[i];
      hcar[i] = hv;                              // register carry
      tile[(rbl + i) * 16 + c] = f2bf(hv);       // LDS repack (intra-wave rows)
    }

    // ---- publish: one contiguous 2KB block per (WG,t), full 64B lines ----
    {
      unsigned long long v = tile64[tid >> 2][tid & 3];
      unsigned long long* dst = hx64 + (size_t)t * (64*4*256)
                              + (((size_t)(p*4 + mg)) << 8) + tid;
      __hip_atomic_store(dst, v, __ATOMIC_RELAXED, __HIP_MEMORY_SCOPE_AGENT);
    }

    // ---- y[t-1] store: bf16, blocked (2KB full-line blocks), workspace ----
    if (doy && t > 0) {
      unsigned short* yblk = ybf + ((((size_t)(t-1)*48 + p)*4 + mg) << 10); // *64*16
      #pragma unroll
      for (int i = 0; i < 4; i++)
        yblk[(rbl + i) * 16 + c] = f2bf(ysum[i] + ybias);
    }
  }

  // ---- post-loop: y[T-1] from step T-1 publishes (consume-only pass) ----
  if (doy) {
    unsigned long long* hxp = hx64 + (size_t)(TLEN - 1) * (64*4*256);
    {
      const unsigned long long* cn = hxp + (((size_t)(cprod*4 + mg)) << 8) + 255;
      for (;;) {
        unsigned long long v = __hip_atomic_load(cn, __ATOMIC_RELAXED, __HIP_MEMORY_SCOPE_AGENT);
        if (__all(v != SENT64)) break;
        __builtin_amdgcn_s_sleep(1);
      }
    }
    u64x2 va[8][4];
    #pragma unroll
    for (int ks = 0; ks < 8; ks++)
      #pragma unroll
      for (int mf = 0; mf < 4; mf++)
        va[ks][mf] = *(const u64x2*)(hxp + (((size_t)((16*w + 2*ks + rp)*4 + mg)) << 8)
                                          + (size_t)(mf*16 + c)*4 + q0);
    unsigned int bad = 0;
    #pragma unroll
    for (int ks = 0; ks < 8; ks++)
      #pragma unroll
      for (int mf = 0; mf < 4; mf++)
        bad |= (unsigned int)(va[ks][mf][0] == SENT64) | (unsigned int)(va[ks][mf][1] == SENT64);
    if (__any((int)bad)) {
      #pragma unroll
      for (int ks = 0; ks < 8; ks++)
        #pragma unroll
        for (int mf = 0; mf < 4; mf++) {
          unsigned long long* pb = hxp + (((size_t)((16*w + 2*ks + rp)*4 + mg)) << 8)
                                       + (size_t)(mf*16 + c)*4 + q0;
          #pragma unroll
          for (int hh = 0; hh < 2; hh++) {
            if (va[ks][mf][hh] == SENT64) {
              unsigned long long v;
              do {
                v = __hip_atomic_load(pb + hh, __ATOMIC_RELAXED, __HIP_MEMORY_SCOPE_AGENT);
              } while (v == SENT64);
              pb[hh] = v;
              va[ks][mf][hh] = v;
            }
          }
        }
    }
    f32x4 yacc[4];
    #pragma unroll
    for (int mf = 0; mf < 4; mf++) yacc[mf] = f32x4{0.f, 0.f, 0.f, 0.f};
    #pragma unroll
    for (int ks = 0; ks < 8; ks++)
      #pragma unroll
      for (int mf = 0; mf < 4; mf++)
        yacc[mf] = __builtin_amdgcn_mfma_f32_16x16x32_bf16(
            __builtin_bit_cast(s16x8, va[ks][mf]), wf[ks], yacc[mf], 0, 0, 0);
    f32x4 ykeep;
    #pragma unroll
    for (int mf = 0; mf < 4; mf++) {
      if (mf != w) redY[w][mf][lane] = yacc[mf];
      else         ykeep = yacc[mf];
    }
    __syncthreads();
    f32x4 ysum = ykeep;
    #pragma unroll
    for (int w2 = 0; w2 < 4; w2++)
      if (w2 != w) ysum += redY[w2][w][lane];
    unsigned short* yblk = ybf + ((((size_t)(TLEN-1)*48 + p)*4 + mg) << 10);
    #pragma unroll
    for (int i = 0; i < 4; i++)
      yblk[(rbl + i) * 16 + c] = f2bf(ysum[i] + ybias);
  }
}

// ---------------- fallback per-step GRU (only if workspace too small) ----------------
__global__ __launch_bounds__(256) void k_gru_step(
    const unsigned short* __restrict__ A1, int K1,
    const unsigned short* __restrict__ W1,
    const float* __restrict__ b1,
    const unsigned short* __restrict__ A2,
    const unsigned short* __restrict__ W2,
    const float* __restrict__ b2,
    const float* __restrict__ hprev,
    float* __restrict__ hout,
    unsigned short* __restrict__ hseq,
    int fused)
{
  __shared__ f32x4 red[4][24][64];
  int ublk = blockIdx.x & 63, mg = blockIdx.x >> 6;
  int u0 = ublk * 16, m0 = mg * 64;
  int w = threadIdx.x >> 6, lane = threadIdx.x & 63;
  int c = lane & 15, klane = (lane >> 4) << 3;
  f32x4 acc[6][4];
  #pragma unroll
  for (int g = 0; g < 6; g++)
    #pragma unroll
    for (int mf = 0; mf < 4; mf++) acc[g][mf] = f32x4{0.f, 0.f, 0.f, 0.f};

  if (fused) {
    const int kpw = HDIM >> 2;
    int kw0 = w * kpw;
    for (int kk = 0; kk < kpw; kk += 32) {
      int kb = kw0 + kk + klane;
      s16x8 a[4], bg[6];
      #pragma unroll
      for (int mf = 0; mf < 4; mf++)
        a[mf] = *(const s16x8*)(A2 + (size_t)(m0 + mf*16 + c) * HDIM + kb);
      #pragma unroll
      for (int g = 0; g < 3; g++) {
        bg[g]   = *(const s16x8*)(W1 + (size_t)(g*HDIM + u0 + c) * HDIM + kb);
        bg[g+3] = *(const s16x8*)(W2 + (size_t)(g*HDIM + u0 + c) * HDIM + kb);
      }
      #pragma unroll
      for (int g = 0; g < 6; g++)
        #pragma unroll
        for (int mf = 0; mf < 4; mf++)
          acc[g][mf] = __builtin_amdgcn_mfma_f32_16x16x32_bf16(a[mf], bg[g], acc[g][mf], 0, 0, 0);
    }
  } else {
    {
      int kpw = K1 >> 2, kw0 = w * kpw;
      for (int kk = 0; kk < kpw; kk += 32) {
        int kb = kw0 + kk + klane;
        s16x8 a[4], bg[3];
        #pragma unroll
        for (int mf = 0; mf < 4; mf++)
          a[mf] = *(const s16x8*)(A1 + (size_t)(m0 + mf*16 + c) * K1 + kb);
        #pragma unroll
        for (int g = 0; g < 3; g++)
          bg[g] = *(const s16x8*)(W1 + (size_t)(g*HDIM + u0 + c) * K1 + kb);
        #pragma unroll
        for (int g = 0; g < 3; g++)
          #pragma unroll
          for (int mf = 0; mf < 4; mf++)
            acc[g][mf] = __builtin_amdgcn_mfma_f32_16x16x32_bf16(a[mf], bg[g], acc[g][mf], 0, 0, 0);
      }
    }
    {
      int kpw = HDIM >> 2, kw0 = w * kpw;
      for (int kk = 0; kk < kpw; kk += 32) {
        int kb = kw0 + kk + klane;
        s16x8 a[4], bg[3];
        #pragma unroll
        for (int mf = 0; mf < 4; mf++)
          a[mf] = *(const s16x8*)(A2 + (size_t)(m0 + mf*16 + c) * HDIM + kb);
        #pragma unroll
        for (int g = 0; g < 3; g++)
          bg[g] = *(const s16x8*)(W2 + (size_t)(g*HDIM + u0 + c) * HDIM + kb);
        #pragma unroll
        for (int g = 0; g < 3; g++)
          #pragma unroll
          for (int mf = 0; mf < 4; mf++)
            acc[g+3][mf] = __builtin_amdgcn_mfma_f32_16x16x32_bf16(a[mf], bg[g], acc[g+3][mf], 0, 0, 0);
      }
    }
  }

  #pragma unroll
  for (int g = 0; g < 6; g++)
    #pragma unroll
    for (int mf = 0; mf < 4; mf++)
      red[w][g*4+mf][lane] = acc[g][mf];
  __syncthreads();

  f32x4 gg[6];
  #pragma unroll
  for (int g = 0; g < 6; g++) {
    f32x4 sum = red[0][g*4+w][lane];
    #pragma unroll
    for (int w2 = 1; w2 < 4; w2++) sum += red[w2][g*4+w][lane];
    gg[g] = sum;
  }
  int u = u0 + c;
  float b1r = b1[u], b1z = b1[HDIM+u], b1n = b1[2*HDIM+u];
  float b2r = b2[u], b2z = b2[HDIM+u], b2n = b2[2*HDIM+u];
  int rb = m0 + w*16 + ((lane >> 4) << 2);
  #pragma unroll
  for (int i = 0; i < 4; i++) {
    float pre_r = gg[0][i] + b1r + gg[3][i] + b2r;
    float pre_z = gg[1][i] + b1z + gg[4][i] + b2z;
    float ghn  = gg[5][i] + b2n;
    float r = 1.f / (1.f + __expf(-pre_r));
    float z = 1.f / (1.f + __expf(-pre_z));
    float pn = gg[2][i] + b1n + r * ghn;
    pn = fminf(fmaxf(pn, -15.f), 15.f);
    float e2 = __expf(2.f * pn);
    float n = (e2 - 1.f) / (e2 + 1.f);
    size_t idx = (size_t)(rb + i) * HDIM + u;
    float hp = hprev[idx];
    float hn = (1.f - z) * n + z * hp;
    hout[idx] = hn;
    hseq[idx] = f2bf(hn);
  }
}

// ---------------- host ----------------

extern "C" void kernel_launch(void* const* d_in, const int* in_sizes, int n_in,
                              void* d_out, int out_size, void* d_ws, size_t ws_size,
                              hipStream_t stream) {
  const float* src    = (const float*)d_in[0];
  const float* hidden = (const float*)d_in[2];
  const float* w_ih   = (const float*)d_in[3];
  const float* w_hh   = (const float*)d_in[4];
  const float* b_ih   = (const float*)d_in[5];
  const float* b_hh   = (const float*)d_in[6];
  const float* w_fc   = (const float*)d_in[7];
  const float* b_fc   = (const float*)d_in[8];
  float* out = (float*)d_out;

  uint8_t* ws = (uint8_t*)d_ws;
  size_t off = 0;
  auto alloc = [&](size_t bytes) -> void* {
    void* pp = ws + off;
    off += (bytes + 255) & ~(size_t)255;
    return pp;
  };
  unsigned short* wih_b  = (unsigned short*)alloc((size_t)G3*ODIM*2);
  unsigned short* whh_b  = (unsigned short*)alloc((size_t)G3*HDIM*2);
  unsigned short* wfc_b  = (unsigned short*)alloc((size_t)ODIM*HDIM*2);
  unsigned short* wfcT_b = (unsigned short*)alloc((size_t)HDIM*ODIM*2);
  unsigned short* wcomb  = (unsigned short*)alloc((size_t)G3*HDIM*2);
  unsigned short* src0_b = (unsigned short*)alloc((size_t)BDIM*ODIM*2);
  unsigned short* h0_b   = (unsigned short*)alloc((size_t)BDIM*HDIM*2);
  float* bcomb = (float*)alloc((size_t)G3*4);
  float* hbuf0 = (float*)alloc((size_t)BDIM*HDIM*4);
  float* hbuf1 = (float*)alloc((size_t)BDIM*HDIM*4);
  unsigned short* hpp = (unsigned short*)alloc((size_t)2*BDIM*HDIM*2);
  unsigned short* hseq = (unsigned short*)alloc((size_t)TLEN*BDIM*HDIM*2);
  float* gi0 = (float*)alloc((size_t)BDIM*G3*4);
  bool big = (off <= ws_size);   // persistent path needs everything up to here
  unsigned short* ybf = (unsigned short*)alloc((size_t)TLEN*48*4*64*16*2);  // 75MB blocked y
  bool fusey = (off <= ws_size); // fused-y path additionally needs ybf

  // prep
  k_f32_to_bf16<<<G3*ODIM/4/256, 256, 0, stream>>>(w_ih, wih_b, G3*ODIM/4);
  k_f32_to_bf16<<<G3*HDIM/4/256, 256, 0, stream>>>(w_hh, whh_b, G3*HDIM/4);
  k_f32_to_bf16<<<ODIM*HDIM/4/256, 256, 0, stream>>>(w_fc, wfc_b, ODIM*HDIM/4);
  k_f32_to_bf16<<<BDIM*ODIM/4/256, 256, 0, stream>>>(src, src0_b, BDIM*ODIM/4);
  k_f32_to_bf16<<<BDIM*HDIM/4/256, 256, 0, stream>>>(hidden, h0_b, BDIM*HDIM/4);
  k_transpose_f32_bf16<<<dim3(HDIM/32, ODIM/32), dim3(32, 8), 0, stream>>>(w_fc, wfcT_b, ODIM, HDIM);
  k_gemm_bt<true, false><<<dim3(G3/64, HDIM/128), 256, 0, stream>>>(wih_b, wfcT_b, nullptr, wcomb, G3, HDIM, ODIM);
  k_bcomb<<<G3/4, 256, 0, stream>>>(w_ih, b_ih, b_fc, bcomb);

  if (big) {
    // sentinel-fill the exchange buffer (REQUIRED every call: harness does
    // not re-poison between replays; protocol self-syncs on 0xFF)
    hipMemsetAsync(hseq, 0xFF, (size_t)TLEN*BDIM*HDIM*2, stream);
    // gi0 = src0 @ w_ih^T + b_ih  (f32, exact input for step 0)
    k_gemm_bt<false, true><<<dim3(BDIM/64, G3/128), 256, 0, stream>>>(
        src0_b, wih_b, b_ih, gi0, BDIM, G3, ODIM);
    // persistent GRU; fused y iff ybf fits in workspace
    k_gru_persist<<<256, 256, 0, stream>>>(h0_b, wcomb, whh_b, bcomb, b_hh,
                                           gi0, hidden, wfc_b, b_fc,
                                           fusey ? ybf : nullptr,
                                           (unsigned long long*)hseq);
    if (fusey) {
      k_y_unblock<<<TLEN*48, 256, 0, stream>>>(ybf, out);
    } else {
      k_gemm_hseq<<<dim3(TLEN*BDIM/64, ODIM/128), 256, 0, stream>>>(
          (const unsigned long long*)hseq, wfc_b, b_fc, out);
    }
  } else {
    for (int t = 0; t < TLEN; t++) {
      const unsigned short* aprev = (t == 0) ? h0_b : hpp + (size_t)((t-1)&1)*BDIM*HDIM;
      unsigned short* hs_cur = hpp + (size_t)(t&1)*BDIM*HDIM;
      const float* hprev_f = (t == 0) ? hidden : ((t & 1) ? hbuf0 : hbuf1);
      float* hout_f = (t & 1) ? hbuf1 : hbuf0;
      if (t == 0) {
        k_gru_step<<<256, 256, 0, stream>>>(src0_b, ODIM, wih_b, b_ih,
            aprev, whh_b, b_hh, hprev_f, hout_f, hs_cur, 0);
      } else {
        k_gru_step<<<256, 256, 0, stream>>>(aprev, HDIM, wcomb, bcomb,
            aprev, whh_b, b_hh, hprev_f, hout_f, hs_cur, 1);
      }
      k_gemm_bt<false, true><<<dim3(BDIM/64, ODIM/128), 256, 0, stream>>>(
          hs_cur, wfc_b, b_fc, out + (size_t)t*BDIM*ODIM, BDIM, ODIM, HDIM);
    }
  }
}

// Round 9
// 2286.926 us; speedup vs baseline: 1.8028x; 1.7970x over previous
//
#include <hip/hip_runtime.h>
#include <stdint.h>

#define HDIM 1024
#define ODIM 768
#define BDIM 256
#define TLEN 256
#define G3 (3*HDIM)

typedef __attribute__((ext_vector_type(4))) float f32x4;
typedef __attribute__((ext_vector_type(8))) short s16x8;
typedef __attribute__((ext_vector_type(2))) unsigned long long u64x2;

#define SENT64 0xFFFFFFFFFFFFFFFFull

static __device__ __forceinline__ unsigned short f2bf(float f) {
  uint32_t u = __builtin_bit_cast(uint32_t, f);
  return (unsigned short)((u + 0x7fffu + ((u >> 16) & 1u)) >> 16);
}

// ---------------- prep kernels ----------------

__global__ void k_f32_to_bf16(const float* __restrict__ in, unsigned short* __restrict__ out, int n4) {
  int i = blockIdx.x * 256 + threadIdx.x;
  if (i >= n4) return;
  float4 v = ((const float4*)in)[i];
  ushort4 o;
  o.x = f2bf(v.x); o.y = f2bf(v.y); o.z = f2bf(v.z); o.w = f2bf(v.w);
  ((ushort4*)out)[i] = o;
}

// in [R][C] f32 -> out [C][R] bf16
__global__ void k_transpose_f32_bf16(const float* __restrict__ in, unsigned short* __restrict__ out, int R, int C) {
  __shared__ float tile[32][33];
  int c0 = blockIdx.x * 32, r0 = blockIdx.y * 32;
  int tx = threadIdx.x, ty = threadIdx.y;
  #pragma unroll
  for (int i = 0; i < 32; i += 8)
    tile[ty + i][tx] = in[(size_t)(r0 + ty + i) * C + (c0 + tx)];
  __syncthreads();
  #pragma unroll
  for (int i = 0; i < 32; i += 8)
    out[(size_t)(c0 + ty + i) * R + (r0 + tx)] = f2bf(tile[tx][ty + i]);
}

// b_comb[c] = b_ih[c] + sum_o w_ih[c][o] * b_fc[o]   (fp32)
__global__ void k_bcomb(const float* __restrict__ w_ih, const float* __restrict__ b_ih,
                        const float* __restrict__ b_fc, float* __restrict__ bc) {
  int gw = (blockIdx.x * 256 + threadIdx.x) >> 6;
  int lane = threadIdx.x & 63;
  if (gw >= G3) return;
  const float* row = w_ih + (size_t)gw * ODIM;
  float s = 0.f;
  for (int o = lane; o < ODIM; o += 64) s += row[o] * b_fc[o];
  #pragma unroll
  for (int off = 32; off; off >>= 1) s += __shfl_down(s, off);
  if (lane == 0) bc[gw] = s + b_ih[gw];
}

// ---------------- generic bf16 GEMM: C[M][N] = A[M][K] * Bm[N][K]^T (+bias) ----------------
template<bool OUT_BF16, bool ADD_BIAS>
__global__ __launch_bounds__(256) void k_gemm_bt(
    const unsigned short* __restrict__ A,
    const unsigned short* __restrict__ Bm,
    const float* __restrict__ bias,
    void* __restrict__ Cout,
    int M, int N, int K)
{
  __shared__ f32x4 red[4][32][64];   // 128 KB
  int m0 = blockIdx.x * 64, n0 = blockIdx.y * 128;
  int w = threadIdx.x >> 6, lane = threadIdx.x & 63;
  int c = lane & 15, klane = (lane >> 4) << 3;
  int kpw = K >> 2, kw0 = w * kpw;
  f32x4 acc[4][8];
  #pragma unroll
  for (int mf = 0; mf < 4; mf++)
    #pragma unroll
    for (int nf = 0; nf < 8; nf++) acc[mf][nf] = f32x4{0.f, 0.f, 0.f, 0.f};

  for (int kk = 0; kk < kpw; kk += 32) {
    int kb = kw0 + kk + klane;
    s16x8 a[4], b[8];
    #pragma unroll
    for (int mf = 0; mf < 4; mf++)
      a[mf] = *(const s16x8*)(A + (size_t)(m0 + mf*16 + c) * K + kb);
    #pragma unroll
    for (int nf = 0; nf < 8; nf++)
      b[nf] = *(const s16x8*)(Bm + (size_t)(n0 + nf*16 + c) * K + kb);
    #pragma unroll
    for (int mf = 0; mf < 4; mf++)
      #pragma unroll
      for (int nf = 0; nf < 8; nf++)
        acc[mf][nf] = __builtin_amdgcn_mfma_f32_16x16x32_bf16(a[mf], b[nf], acc[mf][nf], 0, 0, 0);
  }
  #pragma unroll
  for (int mf = 0; mf < 4; mf++)
    #pragma unroll
    for (int nf = 0; nf < 8; nf++)
      red[w][mf*8+nf][lane] = acc[mf][nf];
  __syncthreads();
  #pragma unroll
  for (int nf = 0; nf < 8; nf++) {
    f32x4 s = red[0][w*8+nf][lane];
    #pragma unroll
    for (int w2 = 1; w2 < 4; w2++) s += red[w2][w*8+nf][lane];
    int col = n0 + nf*16 + c;
    float bv = 0.f;
    if constexpr (ADD_BIAS) bv = bias[col];
    int rb = m0 + w*16 + ((lane >> 4) << 2);
    #pragma unroll
    for (int i = 0; i < 4; i++) {
      float val = s[i] + bv;
      if constexpr (OUT_BF16)
        ((unsigned short*)Cout)[(size_t)(rb + i) * N + col] = f2bf(val);
      else
        ((float*)Cout)[(size_t)(rb + i) * N + col] = val;
    }
  }
}

// ---------------- output GEMM over block-layout hseq ----------------
// A is hseq in BLOCK layout: u64 index = ((t*64 + p')*4 + mg)*256 + rowl*4 + q
// where logical A row r = t*256 + mg*64 + rowl, logical k-cols [16p'+4q ..+4).
__global__ __launch_bounds__(256) void k_gemm_hseq(
    const unsigned long long* __restrict__ Ahx,  // block-layout hseq
    const unsigned short* __restrict__ Bm,       // [N][K] bf16 (w_fc)
    const float* __restrict__ bias,
    float* __restrict__ Cout)
{
  const int N = ODIM, K = HDIM;
  __shared__ f32x4 red[4][32][64];   // 128 KB
  int m0 = blockIdx.x * 64, n0 = blockIdx.y * 128;
  int w = threadIdx.x >> 6, lane = threadIdx.x & 63;
  int c = lane & 15, klane = (lane >> 4) << 3;
  int kpw = K >> 2, kw0 = w * kpw;
  const int tb = m0 >> 8, mgb = (m0 >> 6) & 3;   // m0 is 64-aligned: block-constant
  f32x4 acc[4][8];
  #pragma unroll
  for (int mf = 0; mf < 4; mf++)
    #pragma unroll
    for (int nf = 0; nf < 8; nf++) acc[mf][nf] = f32x4{0.f, 0.f, 0.f, 0.f};

  for (int kk = 0; kk < kpw; kk += 32) {
    int kb = kw0 + kk + klane;
    int uk = kb >> 2;                 // u64 col index; even (klane mult of 8)
    s16x8 a[4], b[8];
    #pragma unroll
    for (int mf = 0; mf < 4; mf++)
      a[mf] = *(const s16x8*)(Ahx + (((size_t)((tb*64 + (uk>>2))*4 + mgb)) << 8)
                                   + (size_t)(mf*16 + c)*4 + (uk & 3));
    #pragma unroll
    for (int nf = 0; nf < 8; nf++)
      b[nf] = *(const s16x8*)(Bm + (size_t)(n0 + nf*16 + c) * K + kb);
    #pragma unroll
    for (int mf = 0; mf < 4; mf++)
      #pragma unroll
      for (int nf = 0; nf < 8; nf++)
        acc[mf][nf] = __builtin_amdgcn_mfma_f32_16x16x32_bf16(a[mf], b[nf], acc[mf][nf], 0, 0, 0);
  }
  #pragma unroll
  for (int mf = 0; mf < 4; mf++)
    #pragma unroll
    for (int nf = 0; nf < 8; nf++)
      red[w][mf*8+nf][lane] = acc[mf][nf];
  __syncthreads();
  #pragma unroll
  for (int nf = 0; nf < 8; nf++) {
    f32x4 s = red[0][w*8+nf][lane];
    #pragma unroll
    for (int w2 = 1; w2 < 4; w2++) s += red[w2][w*8+nf][lane];
    int col = n0 + nf*16 + c;
    float bv = bias[col];
    int rb = m0 + w*16 + ((lane >> 4) << 2);
    #pragma unroll
    for (int i = 0; i < 4; i++)
      Cout[(size_t)(rb + i) * N + col] = s[i] + bv;
  }
}

// ---------------- persistent GRU kernel ----------------
// v10 = EXACT R4 dataflow (best proven: persist 1912us, total 2209us) +
// three surgical, mechanism-understood changes. Fusion of the output GEMM
// is REFUTED (R6/R7/R8: any extra store stream from this kernel wrecks the
// exchange's MALL behavior; k_gemm_hseq at ~190us is cheaper).
//  1. Poll dedupe: only lanes 0-15 issue canary atomics (same 16 producers
//     covered; 4x less MALL poll traffic -- 1024 waves' redundant polls
//     plausibly delay the publishes they await).
//  2. s_sleep(1)->(2): halves steady-state poll rate.
//  3. B3 removed via parity double-buffered red[2][4][18][64] (144KB; rows
//     compacted to 18 since only mf!=w is stored; +tile = 146KB < 160KB,
//     still 1 WG/CU). Step t uses red[t&1]; step t+2's write reuse is
//     fenced transitively by B2(t+1) (every wave passes it only after
//     finishing step t's reads). One barrier per step instead of two.
// Everything else (block-contiguous exchange, optimistic canary + sentinel
// backstop + repair store, publish-after-B2, register h-carry) is R4.
__global__ __launch_bounds__(256, 1) void k_gru_persist(
    const unsigned short* __restrict__ h0b,    // [B][H] bf16 initial h
    const unsigned short* __restrict__ wcomb,  // [3H][H] bf16
    const unsigned short* __restrict__ whh,    // [3H][H] bf16
    const float* __restrict__ bcomb,           // [3H]
    const float* __restrict__ bhh,             // [3H]
    const float* __restrict__ gi0,             // [B][3H] f32 (w_ih@src0+b_ih)
    const float* __restrict__ hidden0,         // [B][H] f32
    unsigned long long* __restrict__ hx64)     // [T*64*4*256] u64 block-layout hseq (sentinel-filled)
{
  __shared__ f32x4 red[2][4][18][64];          // 144 KB (parity double-buffer, compacted rows)
  __shared__ unsigned long long tile64[64][4]; // 2 KB repack tile
  unsigned short* tile = (unsigned short*)tile64;

  const int wg = blockIdx.x;
  const int mg = wg & 3, p = wg >> 2;
  const int tid = threadIdx.x;
  const int w = tid >> 6, lane = tid & 63;
  const int c = lane & 15, klane = (lane >> 4) << 3, rq = (lane >> 4) << 2;
  const int u0 = p * 16, u = u0 + c, m0 = mg * 64;
  const int wk0 = w * 256;
  const int rp = lane >> 5;                    // p' sub-offset within a ks pair (0/1)
  const int q0 = ((lane >> 4) & 1) << 1;       // u64 q within block (0/2)
  const int cprod = 16 * w + (lane & 15);      // canary producer (lanes 0-15 poll)
  const int rbl = w*16 + rq;                   // row within the 64-row block

  // per-lane biases (unit u), constant across t
  const float bcr = bcomb[u], bcz = bcomb[HDIM + u], bcn = bcomb[2*HDIM + u];
  const float bhr = bhh[u],   bhz = bhh[HDIM + u],   bhn = bhh[2*HDIM + u];

  // load weight b-frags into registers: wr[gate][kstep]  (192 regs, AV file)
  s16x8 wr[6][8];
  #pragma unroll
  for (int g = 0; g < 6; g++) {
    const unsigned short* W = (g < 3) ? (wcomb + (size_t)g * HDIM * HDIM)
                                      : (whh   + (size_t)(g - 3) * HDIM * HDIM);
    const unsigned short* Wrow = W + (size_t)(u0 + c) * HDIM + wk0 + klane;
    #pragma unroll
    for (int ks = 0; ks < 8; ks++)
      wr[g][ks] = *(const s16x8*)(Wrow + ks * 32);
  }

  float hcar[4];   // fp32 h carry, (r,u) fixed per thread

  #pragma unroll 1
  for (int t = 0; t < TLEN; t++) {
    // ---- A-frag acquisition ----
    s16x8 a[8][4];
    if (t == 0) {
      #pragma unroll
      for (int ks = 0; ks < 8; ks++)
        #pragma unroll
        for (int mf = 0; mf < 4; mf++)
          a[ks][mf] = *(const s16x8*)(h0b + (size_t)(m0 + mf*16 + c) * HDIM + wk0 + ks*32 + klane);
    } else {
      unsigned long long* hxp = hx64 + (size_t)(t - 1) * (64*4*256);
      // per-wave canary, DEDUPED: lanes 0-15 poll the LAST u64 of producer
      // block (cprod = 16w + lane, mg); lanes 16-63 idle (they previously
      // polled the same 16 addresses redundantly). Heuristic gate; the
      // backstop below is the correctness.
      {
        const unsigned long long* cn = hxp + (((size_t)(cprod*4 + mg)) << 8) + 255;
        for (;;) {
          unsigned long long v = 0;
          if (lane < 16)
            v = __hip_atomic_load(cn, __ATOMIC_RELAXED, __HIP_MEMORY_SCOPE_AGENT);
          if (__all(lane >= 16 || v != SENT64)) break;
          __builtin_amdgcn_s_sleep(2);
        }
      }
      // bulk fast path: coalesced 16B regular loads (half-wave reads a
      // contiguous 512B span of producer block (16w+2ks+rp, mg))
      u64x2 va[8][4];
      #pragma unroll
      for (int ks = 0; ks < 8; ks++)
        #pragma unroll
        for (int mf = 0; mf < 4; mf++)
          va[ks][mf] = *(const u64x2*)(hxp + (((size_t)((16*w + 2*ks + rp)*4 + mg)) << 8)
                                            + (size_t)(mf*16 + c)*4 + q0);
      // backstop: per-u64 sentinel validation; atomic re-poll + repair
      unsigned int bad = 0;
      #pragma unroll
      for (int ks = 0; ks < 8; ks++)
        #pragma unroll
        for (int mf = 0; mf < 4; mf++)
          bad |= (unsigned int)(va[ks][mf][0] == SENT64) | (unsigned int)(va[ks][mf][1] == SENT64);
      if (__any((int)bad)) {
        #pragma unroll
        for (int ks = 0; ks < 8; ks++)
          #pragma unroll
          for (int mf = 0; mf < 4; mf++) {
            unsigned long long* pb = hxp + (((size_t)((16*w + 2*ks + rp)*4 + mg)) << 8)
                                         + (size_t)(mf*16 + c)*4 + q0;
            #pragma unroll
            for (int hh = 0; hh < 2; hh++) {
              if (va[ks][mf][hh] == SENT64) {
                unsigned long long v;
                do {
                  v = __hip_atomic_load(pb + hh, __ATOMIC_RELAXED, __HIP_MEMORY_SCOPE_AGENT);
                } while (v == SENT64);
                pb[hh] = v;            // repair stale local-L2 line (same value, benign)
                va[ks][mf][hh] = v;
              }
            }
          }
      }
      #pragma unroll
      for (int ks = 0; ks < 8; ks++)
        #pragma unroll
        for (int mf = 0; mf < 4; mf++)
          a[ks][mf] = __builtin_bit_cast(s16x8, va[ks][mf]);
    }

    // ---- MFMA phase ----
    f32x4 acc[4][6];
    #pragma unroll
    for (int mf = 0; mf < 4; mf++)
      #pragma unroll
      for (int g = 0; g < 6; g++) acc[mf][g] = f32x4{0.f, 0.f, 0.f, 0.f};
    #pragma unroll
    for (int ks = 0; ks < 8; ks++)
      #pragma unroll
      for (int g = 0; g < 6; g++)
        #pragma unroll
        for (int mf = 0; mf < 4; mf++)
          acc[mf][g] = __builtin_amdgcn_mfma_f32_16x16x32_bf16(a[ks][mf], wr[g][ks], acc[mf][g], 0, 0, 0);

    // ---- cross-wave K-reduce (parity buffer red[t&1]): wave w keeps mf==w ----
    f32x4 (*redc)[18][64] = red[t & 1];
    #pragma unroll
    for (int mf = 0; mf < 4; mf++) {
      if (mf != w) {
        const int rbase = (mf < w ? mf : mf - 1) * 6;
        #pragma unroll
        for (int g = 0; g < 6; g++) redc[w][rbase + g][lane] = acc[mf][g];
      }
    }
    f32x4 s[6];
    #pragma unroll
    for (int mf = 0; mf < 4; mf++) {
      if (mf == w) {
        #pragma unroll
        for (int g = 0; g < 6; g++) s[g] = acc[mf][g];
      }
    }
    __syncthreads();   // B2: red[t&1] writes complete. (Also transitively
                       // fences step t-2's reads of this buffer: every wave
                       // passed B2(t-1) only after finishing them.)
    #pragma unroll
    for (int w2 = 0; w2 < 4; w2++) {
      if (w2 != w) {
        const int rbase = (w < w2 ? w : w - 1) * 6;
        #pragma unroll
        for (int g = 0; g < 6; g++) s[g] += redc[w2][rbase + g][lane];
      }
    }
    // NO B3: next step writes red[(t+1)&1] (disjoint); tile rows are
    // wave-private (intra-wave ordering suffices).

    // ---- epilogue: rows m0 + rbl + i, unit u ----
    #pragma unroll
    for (int i = 0; i < 4; i++) {
      int r = m0 + rbl + i;
      float gir, giz, gin;
      if (t == 0) {
        gir = gi0[(size_t)r * G3 + u];
        giz = gi0[(size_t)r * G3 + HDIM + u];
        gin = gi0[(size_t)r * G3 + 2*HDIM + u];
        hcar[i] = hidden0[(size_t)r * HDIM + u];
      } else {
        gir = s[0][i] + bcr; giz = s[1][i] + bcz; gin = s[2][i] + bcn;
      }
      float ghr = s[3][i] + bhr, ghz = s[4][i] + bhz, ghn = s[5][i] + bhn;
      float rg = 1.f / (1.f + __expf(-(gir + ghr)));
      float zg = 1.f / (1.f + __expf(-(giz + ghz)));
      float pn = gin + rg * ghn;
      pn = fminf(fmaxf(pn, -15.f), 15.f);
      float e2 = __expf(2.f * pn);
      float ng = (e2 - 1.f) / (e2 + 1.f);
      float hv = (1.f - zg) * ng + zg * hcar[i];
      hcar[i] = hv;                              // register carry
      tile[(rbl + i) * 16 + c] = f2bf(hv);       // LDS repack (intra-wave rows)
    }

    // ---- publish: one contiguous 2KB block per (WG,t), full 64B lines ----
    // tile rows [w*16,w*16+16) written by this same wave (in-wave lgkmcnt
    // ordering suffices, no barrier). Stores drain in the shadow of the
    // next step's gate+loads+MFMA.
    {
      unsigned long long v = tile64[tid >> 2][tid & 3];
      unsigned long long* dst = hx64 + (size_t)t * (64*4*256)
                              + (((size_t)(p*4 + mg)) << 8) + tid;
      __hip_atomic_store(dst, v, __ATOMIC_RELAXED, __HIP_MEMORY_SCOPE_AGENT);
    }
  }
}

// ---------------- fallback per-step GRU (only if workspace too small) ----------------
__global__ __launch_bounds__(256) void k_gru_step(
    const unsigned short* __restrict__ A1, int K1,
    const unsigned short* __restrict__ W1,
    const float* __restrict__ b1,
    const unsigned short* __restrict__ A2,
    const unsigned short* __restrict__ W2,
    const float* __restrict__ b2,
    const float* __restrict__ hprev,
    float* __restrict__ hout,
    unsigned short* __restrict__ hseq,
    int fused)
{
  __shared__ f32x4 red[4][24][64];
  int ublk = blockIdx.x & 63, mg = blockIdx.x >> 6;
  int u0 = ublk * 16, m0 = mg * 64;
  int w = threadIdx.x >> 6, lane = threadIdx.x & 63;
  int c = lane & 15, klane = (lane >> 4) << 3;
  f32x4 acc[6][4];
  #pragma unroll
  for (int g = 0; g < 6; g++)
    #pragma unroll
    for (int mf = 0; mf < 4; mf++) acc[g][mf] = f32x4{0.f, 0.f, 0.f, 0.f};

  if (fused) {
    const int kpw = HDIM >> 2;
    int kw0 = w * kpw;
    for (int kk = 0; kk < kpw; kk += 32) {
      int kb = kw0 + kk + klane;
      s16x8 a[4], bg[6];
      #pragma unroll
      for (int mf = 0; mf < 4; mf++)
        a[mf] = *(const s16x8*)(A2 + (size_t)(m0 + mf*16 + c) * HDIM + kb);
      #pragma unroll
      for (int g = 0; g < 3; g++) {
        bg[g]   = *(const s16x8*)(W1 + (size_t)(g*HDIM + u0 + c) * HDIM + kb);
        bg[g+3] = *(const s16x8*)(W2 + (size_t)(g*HDIM + u0 + c) * HDIM + kb);
      }
      #pragma unroll
      for (int g = 0; g < 6; g++)
        #pragma unroll
        for (int mf = 0; mf < 4; mf++)
          acc[g][mf] = __builtin_amdgcn_mfma_f32_16x16x32_bf16(a[mf], bg[g], acc[g][mf], 0, 0, 0);
    }
  } else {
    {
      int kpw = K1 >> 2, kw0 = w * kpw;
      for (int kk = 0; kk < kpw; kk += 32) {
        int kb = kw0 + kk + klane;
        s16x8 a[4], bg[3];
        #pragma unroll
        for (int mf = 0; mf < 4; mf++)
          a[mf] = *(const s16x8*)(A1 + (size_t)(m0 + mf*16 + c) * K1 + kb);
        #pragma unroll
        for (int g = 0; g < 3; g++)
          bg[g] = *(const s16x8*)(W1 + (size_t)(g*HDIM + u0 + c) * K1 + kb);
        #pragma unroll
        for (int g = 0; g < 3; g++)
          #pragma unroll
          for (int mf = 0; mf < 4; mf++)
            acc[g][mf] = __builtin_amdgcn_mfma_f32_16x16x32_bf16(a[mf], bg[g], acc[g][mf], 0, 0, 0);
      }
    }
    {
      int kpw = HDIM >> 2, kw0 = w * kpw;
      for (int kk = 0; kk < kpw; kk += 32) {
        int kb = kw0 + kk + klane;
        s16x8 a[4], bg[3];
        #pragma unroll
        for (int mf = 0; mf < 4; mf++)
          a[mf] = *(const s16x8*)(A2 + (size_t)(m0 + mf*16 + c) * HDIM + kb);
        #pragma unroll
        for (int g = 0; g < 3; g++)
          bg[g] = *(const s16x8*)(W2 + (size_t)(g*HDIM + u0 + c) * HDIM + kb);
        #pragma unroll
        for (int g = 0; g < 3; g++)
          #pragma unroll
          for (int mf = 0; mf < 4; mf++)
            acc[g+3][mf] = __builtin_amdgcn_mfma_f32_16x16x32_bf16(a[mf], bg[g], acc[g+3][mf], 0, 0, 0);
      }
    }
  }

  #pragma unroll
  for (int g = 0; g < 6; g++)
    #pragma unroll
    for (int mf = 0; mf < 4; mf++)
      red[w][g*4+mf][lane] = acc[g][mf];
  __syncthreads();

  f32x4 gg[6];
  #pragma unroll
  for (int g = 0; g < 6; g++) {
    f32x4 sum = red[0][g*4+w][lane];
    #pragma unroll
    for (int w2 = 1; w2 < 4; w2++) sum += red[w2][g*4+w][lane];
    gg[g] = sum;
  }
  int u = u0 + c;
  float b1r = b1[u], b1z = b1[HDIM+u], b1n = b1[2*HDIM+u];
  float b2r = b2[u], b2z = b2[HDIM+u], b2n = b2[2*HDIM+u];
  int rb = m0 + w*16 + ((lane >> 4) << 2);
  #pragma unroll
  for (int i = 0; i < 4; i++) {
    float pre_r = gg[0][i] + b1r + gg[3][i] + b2r;
    float pre_z = gg[1][i] + b1z + gg[4][i] + b2z;
    float ghn  = gg[5][i] + b2n;
    float r = 1.f / (1.f + __expf(-pre_r));
    float z = 1.f / (1.f + __expf(-pre_z));
    float pn = gg[2][i] + b1n + r * ghn;
    pn = fminf(fmaxf(pn, -15.f), 15.f);
    float e2 = __expf(2.f * pn);
    float n = (e2 - 1.f) / (e2 + 1.f);
    size_t idx = (size_t)(rb + i) * HDIM + u;
    float hp = hprev[idx];
    float hn = (1.f - z) * n + z * hp;
    hout[idx] = hn;
    hseq[idx] = f2bf(hn);
  }
}

// ---------------- host ----------------

extern "C" void kernel_launch(void* const* d_in, const int* in_sizes, int n_in,
                              void* d_out, int out_size, void* d_ws, size_t ws_size,
                              hipStream_t stream) {
  const float* src    = (const float*)d_in[0];
  const float* hidden = (const float*)d_in[2];
  const float* w_ih   = (const float*)d_in[3];
  const float* w_hh   = (const float*)d_in[4];
  const float* b_ih   = (const float*)d_in[5];
  const float* b_hh   = (const float*)d_in[6];
  const float* w_fc   = (const float*)d_in[7];
  const float* b_fc   = (const float*)d_in[8];
  float* out = (float*)d_out;

  uint8_t* ws = (uint8_t*)d_ws;
  size_t off = 0;
  auto alloc = [&](size_t bytes) -> void* {
    void* pp = ws + off;
    off += (bytes + 255) & ~(size_t)255;
    return pp;
  };
  unsigned short* wih_b  = (unsigned short*)alloc((size_t)G3*ODIM*2);
  unsigned short* whh_b  = (unsigned short*)alloc((size_t)G3*HDIM*2);
  unsigned short* wfc_b  = (unsigned short*)alloc((size_t)ODIM*HDIM*2);
  unsigned short* wfcT_b = (unsigned short*)alloc((size_t)HDIM*ODIM*2);
  unsigned short* wcomb  = (unsigned short*)alloc((size_t)G3*HDIM*2);
  unsigned short* src0_b = (unsigned short*)alloc((size_t)BDIM*ODIM*2);
  unsigned short* h0_b   = (unsigned short*)alloc((size_t)BDIM*HDIM*2);
  float* bcomb = (float*)alloc((size_t)G3*4);
  float* hbuf0 = (float*)alloc((size_t)BDIM*HDIM*4);
  float* hbuf1 = (float*)alloc((size_t)BDIM*HDIM*4);
  unsigned short* hpp = (unsigned short*)alloc((size_t)2*BDIM*HDIM*2);
  unsigned short* hseq = (unsigned short*)alloc((size_t)TLEN*BDIM*HDIM*2);
  float* gi0 = (float*)alloc((size_t)BDIM*G3*4);
  bool big = (off <= ws_size);   // persistent path needs everything

  // prep
  k_f32_to_bf16<<<G3*ODIM/4/256, 256, 0, stream>>>(w_ih, wih_b, G3*ODIM/4);
  k_f32_to_bf16<<<G3*HDIM/4/256, 256, 0, stream>>>(w_hh, whh_b, G3*HDIM/4);
  k_f32_to_bf16<<<ODIM*HDIM/4/256, 256, 0, stream>>>(w_fc, wfc_b, ODIM*HDIM/4);
  k_f32_to_bf16<<<BDIM*ODIM/4/256, 256, 0, stream>>>(src, src0_b, BDIM*ODIM/4);
  k_f32_to_bf16<<<BDIM*HDIM/4/256, 256, 0, stream>>>(hidden, h0_b, BDIM*HDIM/4);
  k_transpose_f32_bf16<<<dim3(HDIM/32, ODIM/32), dim3(32, 8), 0, stream>>>(w_fc, wfcT_b, ODIM, HDIM);
  k_gemm_bt<true, false><<<dim3(G3/64, HDIM/128), 256, 0, stream>>>(wih_b, wfcT_b, nullptr, wcomb, G3, HDIM, ODIM);
  k_bcomb<<<G3/4, 256, 0, stream>>>(w_ih, b_ih, b_fc, bcomb);

  if (big) {
    // sentinel-fill the exchange buffer (REQUIRED every call: harness does
    // not re-poison between replays; protocol self-syncs on 0xFF)
    hipMemsetAsync(hseq, 0xFF, (size_t)TLEN*BDIM*HDIM*2, stream);
    // gi0 = src0 @ w_ih^T + b_ih  (f32, exact input for step 0)
    k_gemm_bt<false, true><<<dim3(BDIM/64, G3/128), 256, 0, stream>>>(
        src0_b, wih_b, b_ih, gi0, BDIM, G3, ODIM);
    k_gru_persist<<<256, 256, 0, stream>>>(h0_b, wcomb, whh_b, bcomb, b_hh,
                                           gi0, hidden,
                                           (unsigned long long*)hseq);
    // batched output GEMM over block-layout hseq
    k_gemm_hseq<<<dim3(TLEN*BDIM/64, ODIM/128), 256, 0, stream>>>(
        (const unsigned long long*)hseq, wfc_b, b_fc, out);
  } else {
    for (int t = 0; t < TLEN; t++) {
      const unsigned short* aprev = (t == 0) ? h0_b : hpp + (size_t)((t-1)&1)*BDIM*HDIM;
      unsigned short* hs_cur = hpp + (size_t)(t&1)*BDIM*HDIM;
      const float* hprev_f = (t == 0) ? hidden : ((t & 1) ? hbuf0 : hbuf1);
      float* hout_f = (t & 1) ? hbuf1 : hbuf0;
      if (t == 0) {
        k_gru_step<<<256, 256, 0, stream>>>(src0_b, ODIM, wih_b, b_ih,
            aprev, whh_b, b_hh, hprev_f, hout_f, hs_cur, 0);
      } else {
        k_gru_step<<<256, 256, 0, stream>>>(aprev, HDIM, wcomb, bcomb,
            aprev, whh_b, b_hh, hprev_f, hout_f, hs_cur, 1);
      }
      k_gemm_bt<false, true><<<dim3(BDIM/64, ODIM/128), 256, 0, stream>>>(
          hs_cur, wfc_b, b_fc, out + (size_t)t*BDIM*ODIM, BDIM, ODIM, HDIM);
    }
  }
}